// Round 15
// baseline (500.575 us; speedup 1.0000x reference)
//
#include <hip/hip_runtime.h>
#include <hip/hip_bf16.h>

typedef __hip_bfloat16 bf16;
typedef __attribute__((ext_vector_type(4))) float f32x4;
typedef __attribute__((ext_vector_type(8))) short s16x8;

#define N_TOK 4096   // B*S
#define Dm    512
#define Fm    2048
#define Em    8

__device__ __forceinline__ float bf2f(bf16 v) { return __bfloat162float(v); }
__device__ __forceinline__ bf16  f2bf(float f) { return __float2bfloat16(f); }

// async global->LDS, 16B per lane; LDS dest is wave-uniform base + lane*16
#define GL16(g, l)                                                              \
  __builtin_amdgcn_global_load_lds(                                             \
      (const __attribute__((address_space(1))) void*)(g),                       \
      (__attribute__((address_space(3))) void*)(l), 16, 0, 0)

#define BAR()                                   \
  do {                                          \
    __builtin_amdgcn_s_barrier();               \
    asm volatile("" ::: "memory");              \
  } while (0)

// ---------------- fp32 -> bf16 flat convert ----------------------------------
__global__ void cvt_f32_bf16(const float* __restrict__ in, bf16* __restrict__ out, int n4) {
  int i = blockIdx.x * 256 + threadIdx.x;
  if (i >= n4) return;
  float4 v = reinterpret_cast<const float4*>(in)[i];
  bf16 tmp[4] = {f2bf(v.x), f2bf(v.y), f2bf(v.z), f2bf(v.w)};
  __builtin_memcpy(out + (size_t)i * 4, tmp, 8);
}

// ---------------- fp32 [R][C] -> bf16 [C][R] tiled transpose-convert ---------
__global__ void transpose_cvt(const float* __restrict__ in, bf16* __restrict__ out,
                              int R, int C, long inb, long outb) {
  in  += (long)blockIdx.z * inb;
  out += (long)blockIdx.z * outb;
  __shared__ float t[32][33];
  int tx = threadIdx.x & 31, ty = threadIdx.x >> 5;
  int c0 = blockIdx.x * 32, r0 = blockIdx.y * 32;
#pragma unroll
  for (int i = 0; i < 32; i += 8)
    t[ty + i][tx] = in[(long)(r0 + ty + i) * C + c0 + tx];
  __syncthreads();
#pragma unroll
  for (int i = 0; i < 32; i += 8)
    out[(long)(c0 + ty + i) * R + r0 + tx] = f2bf(t[tx][ty + i]);
}

// ===== 128x64 bf16 GEMM, B-staged / A-direct, occupancy-first (r15) ==========
// C = A @ Bt^T (+bias[, relu]).  A:[M][K] lda, Bt:[N][K] ldb, C row-major ldc.
//
// r14 post-mortem: occupancy was REGISTER-limited all along (AGPR counts in
// the unified file, m69 halving law): 256² tile = acc128+~100 = 228 regs ->
// 8 waves/CU (19%) regardless of schedule; 128² = 128 regs -> 16 waves (38%).
// Latency accounting: component floors (MFMA 33us, HBM 33, LDS 11) vs 103us
// measured => ~70us un-hidden latency. Fix = more resident waves:
//   - wave tile 32x64, acc[2][4] = 32 AGPR; target ~92 regs -> 5 waves/SIMD
//     = 20 waves/CU (__launch_bounds__(256,5)).
//   - block 128x64, 4 waves stacked in M. A rows are used by exactly ONE
//     wave -> staging A through LDS buys nothing; A fragments load DIRECT
//     from L2 (global_load_dwordx4, 16 rows x 64B coalesced). B panel keeps
//     4x in-block reuse -> stays in LDS (double-buffered 2x8KB, BK=64).
//   - ONE barrier + vmcnt(0) per K-tile (audited: top-of-t drain makes B(t)
//     visible; all waves finished reading buf(t-1) pre-barrier, so staging
//     buf((t+1)&1)==buf((t-1)&1) after it is safe). Issue-to-wait = 1 tile.
//   - B chunk-XOR swizzle both sides (#21): LDS chunk (row, s') holds
//     logical k-chunk s'^(row&7); reads spread 16B-slots across all 8
//     positions (b128 floor, no same-bank serialization).
// A re-reads (x32 block-columns) hit L2, not HBM -> FETCH_SIZE unchanged.
template <bool RELU, bool OUT_BF16>
__global__ __launch_bounds__(256, 5) void gemm_bs(
    const bf16* __restrict__ A, const bf16* __restrict__ Bt, void* __restrict__ Cout,
    const float* __restrict__ bias, int K, int lda, int ldb, int ldc,
    long abs_, long bbs, long cbs, long biasbs) {
  __shared__ bf16 Bs[2][64 * 64];  // 16 KB total

  int e = blockIdx.z;
  A    += (long)e * abs_;
  Bt   += (long)e * bbs;
  bias += (long)e * biasbs;
  long coff = (long)e * cbs;

  int bm = blockIdx.x * 128, bn = blockIdx.y * 64;
  int tid = threadIdx.x, wv = tid >> 6, lane = tid & 63;
  int la = lane & 15, q = lane >> 4;

  const bf16* Bb = Bt + (long)bn * ldb;
  int nt = K >> 6;  // BK = 64

  // staging: 512 chunks (64 rows x 8 slots x 16B); thread covers 2 chunks
  int c0 = wv * 128 + lane;
  auto stage = [&](int t) {
    if (t >= nt) return;
    int k0 = t << 6;
    bf16* buf = &Bs[t & 1][0];
#pragma unroll
    for (int j = 0; j < 2; ++j) {
      int c   = c0 + j * 64;
      int row = c >> 3;
      int src = (c & 7) ^ (row & 7);  // inverse-swizzled logical k-chunk
      GL16(Bb + (long)row * ldb + k0 + src * 8, buf + (wv * 128 + j * 64) * 8);
    }
  };

  // A-direct fragment pointers: wave wv owns rows bm + wv*32 .. +32
  const bf16* Ar[2];
#pragma unroll
  for (int mi = 0; mi < 2; ++mi)
    Ar[mi] = A + (long)(bm + wv * 32 + mi * 16 + la) * lda + q * 8;

  f32x4 acc[2][4] = {};

  stage(0);  // prologue

  for (int t = 0; t < nt; ++t) {
    asm volatile("s_waitcnt vmcnt(0)" ::: "memory");  // B(t) staged & visible
    BAR();
    stage(t + 1);  // into buf((t+1)&1); safe post-barrier
    const bf16* Bbuf = &Bs[t & 1][0];
    int k0 = t << 6;
    s16x8 a[2][2], b[4][2];
#pragma unroll
    for (int mi = 0; mi < 2; ++mi)
#pragma unroll
      for (int kk = 0; kk < 2; ++kk)
        a[mi][kk] = *reinterpret_cast<const s16x8*>(Ar[mi] + k0 + kk * 32);
#pragma unroll
    for (int n = 0; n < 4; ++n) {
      int r = n * 16 + la;
#pragma unroll
      for (int kk = 0; kk < 2; ++kk) {
        int ph = (kk * 4 + q) ^ (r & 7);  // swizzled 16B-slot
        b[n][kk] = *reinterpret_cast<const s16x8*>(Bbuf + (r * 8 + ph) * 8);
      }
    }
    __builtin_amdgcn_s_setprio(1);
#pragma unroll
    for (int mi = 0; mi < 2; ++mi)
#pragma unroll
      for (int n = 0; n < 4; ++n)
#pragma unroll
        for (int kk = 0; kk < 2; ++kk)
          acc[mi][n] = __builtin_amdgcn_mfma_f32_16x16x32_bf16(b[n][kk], a[mi][kk],
                                                               acc[mi][n], 0, 0, 0);
    __builtin_amdgcn_s_setprio(0);
  }

  // epilogue: acc[mi][n][r] -> C[bm+wv*32+mi*16+la][bn+n*16+q*4+r]
#pragma unroll
  for (int mi = 0; mi < 2; ++mi) {
    int gm = bm + wv * 32 + mi * 16 + la;
#pragma unroll
    for (int n = 0; n < 4; ++n) {
      int gn = bn + n * 16 + q * 4;
      float4 b4 = *reinterpret_cast<const float4*>(bias + gn);
      float v0 = acc[mi][n][0] + b4.x, v1 = acc[mi][n][1] + b4.y;
      float v2 = acc[mi][n][2] + b4.z, v3 = acc[mi][n][3] + b4.w;
      if (RELU) {
        v0 = fmaxf(v0, 0.f); v1 = fmaxf(v1, 0.f);
        v2 = fmaxf(v2, 0.f); v3 = fmaxf(v3, 0.f);
      }
      long idx = coff + (long)gm * ldc + gn;
      if (OUT_BF16) {
        bf16 tmp[4] = {f2bf(v0), f2bf(v1), f2bf(v2), f2bf(v3)};
        __builtin_memcpy((bf16*)Cout + idx, tmp, 8);
      } else {
        float tmp[4] = {v0, v1, v2, v3};
        __builtin_memcpy((float*)Cout + idx, tmp, 16);
      }
    }
  }
}

// ---------------- 128x128 BK=32 bf16 GEMM (round-1 skeleton; Q & out-proj) ---
template <bool RELU, bool OUT_BF16>
__global__ __launch_bounds__(256, 2) void gemm_bt(
    const bf16* __restrict__ A, const bf16* __restrict__ Bt, void* __restrict__ Cout,
    const float* __restrict__ bias, int M, int N, int K, int lda, int ldb, int ldc,
    long abs_, long bbs, long cbs, long biasbs, const int* __restrict__ eid,
    int eid_scale) {
  int e = blockIdx.z;
  A    += (long)e * abs_;
  Bt   += (long)e * bbs;
  bias += (long)e * biasbs;
  long coff = (long)e * cbs;
  if (eid) A += (long)(*eid) * eid_scale;

  __shared__ bf16 As[128 * 32];
  __shared__ bf16 Bs[128 * 32];

  int tid = threadIdx.x;
  int wave = tid >> 6, lane = tid & 63;
  int wm = wave >> 1, wn = wave & 1;
  int bm = blockIdx.x * 128, bn = blockIdx.y * 128;

  int srow  = lane >> 2;
  int skoff = (lane & 3) * 8;

  f32x4 acc[4][4] = {};

  const bf16* Abase = A + (long)bm * lda;
  const bf16* Bbase = Bt + (long)bn * ldb;

  for (int k0 = 0; k0 < K; k0 += 32) {
    __syncthreads();
#pragma unroll
    for (int i = 0; i < 2; i++) {
      int r = wave * 32 + i * 16 + srow;
      GL16(Abase + (long)r * lda + k0 + skoff, As + (wave * 32 + i * 16) * 32);
      GL16(Bbase + (long)r * ldb + k0 + skoff, Bs + (wave * 32 + i * 16) * 32);
    }
    __syncthreads();

    s16x8 af[4], bfr[4];
#pragma unroll
    for (int m = 0; m < 4; m++)
      af[m] = *reinterpret_cast<const s16x8*>(As + (wm * 64 + m * 16 + (lane & 15)) * 32 +
                                              (lane >> 4) * 8);
#pragma unroll
    for (int n = 0; n < 4; n++)
      bfr[n] = *reinterpret_cast<const s16x8*>(Bs + (wn * 64 + n * 16 + (lane & 15)) * 32 +
                                               (lane >> 4) * 8);
#pragma unroll
    for (int m = 0; m < 4; m++)
#pragma unroll
      for (int n = 0; n < 4; n++)
        acc[m][n] = __builtin_amdgcn_mfma_f32_16x16x32_bf16(af[m], bfr[n], acc[m][n], 0, 0, 0);
  }

  int cr = (lane >> 4) * 4, cc = lane & 15;
#pragma unroll
  for (int m = 0; m < 4; m++) {
#pragma unroll
    for (int n = 0; n < 4; n++) {
      int col  = bn + wn * 64 + n * 16 + cc;
      float bv = bias ? bias[col] : 0.0f;
#pragma unroll
      for (int r = 0; r < 4; r++) {
        int row = bm + wm * 64 + m * 16 + cr + r;
        float v = acc[m][n][r] + bv;
        if (RELU) v = fmaxf(v, 0.0f);
        long idx = coff + (long)row * ldc + col;
        if (OUT_BF16)
          ((bf16*)Cout)[idx] = f2bf(v);
        else
          ((float*)Cout)[idx] = v;
      }
    }
  }
}

// ---------------- attention over the expert axis (E=8, H=8, HD=64) ----------
__global__ __launch_bounds__(256) void attn_kernel(const float* __restrict__ q,
                                                   const bf16* __restrict__ kv,
                                                   bf16* __restrict__ ctx,
                                                   const int* __restrict__ eid) {
  int wave = threadIdx.x >> 6, lane = threadIdx.x & 63;
  int n = blockIdx.x * 4 + wave;
  int h = lane >> 3, f = lane & 7;
  int e3 = *eid;
  const bf16* kvn = kv + (long)n * Em * (2 * Dm);
  const float* qh = q + (long)n * Dm + h * 64;
  const bf16* kf = kvn + f * (2 * Dm) + h * 64;
  float s = 0.f;
#pragma unroll
  for (int j = 0; j < 64; j++) s += qh[j] * bf2f(kf[j]);
  s *= 0.125f;
  s += (f <= e3) ? 1.0f : 0.0f;  // torch-faithful ADDITIVE float tril mask
  float mx = s;
#pragma unroll
  for (int d = 1; d < 8; d <<= 1) mx = fmaxf(mx, __shfl_xor(mx, d));
  float ex = expf(s - mx);
  float sm = ex;
#pragma unroll
  for (int d = 1; d < 8; d <<= 1) sm += __shfl_xor(sm, d);
  float at = ex / sm;
  int g = f;
  float acc[8] = {0, 0, 0, 0, 0, 0, 0, 0};
#pragma unroll
  for (int f2 = 0; f2 < 8; f2++) {
    float a = __shfl(at, (h << 3) | f2);
    const bf16* vf = kvn + f2 * (2 * Dm) + Dm + h * 64 + g * 8;
#pragma unroll
    for (int j = 0; j < 8; j++) acc[j] += a * bf2f(vf[j]);
  }
  bf16 tmp[8];
#pragma unroll
  for (int j = 0; j < 8; j++) tmp[j] = f2bf(acc[j]);
  __builtin_memcpy(ctx + (long)n * Dm + h * 64 + g * 8, tmp, 16);
}

extern "C" void kernel_launch(void* const* d_in, const int* in_sizes, int n_in,
                              void* d_out, int out_size, void* d_ws, size_t ws_size,
                              hipStream_t stream) {
  const float* x  = (const float*)d_in[0];
  const float* W1 = (const float*)d_in[1];
  const float* b1 = (const float*)d_in[2];
  const float* W2 = (const float*)d_in[3];
  const float* b2 = (const float*)d_in[4];
  const float* Wq = (const float*)d_in[5];
  const float* bq = (const float*)d_in[6];
  const float* Wk = (const float*)d_in[7];
  const float* bk = (const float*)d_in[8];
  const float* Wv = (const float*)d_in[9];
  const float* bv = (const float*)d_in[10];
  const float* Wo = (const float*)d_in[11];
  const float* bo = (const float*)d_in[12];
  const int* eid  = (const int*)d_in[13];

  char* w = (char*)d_ws;
  auto alloc = [&](size_t bytes) {
    char* p = w;
    w += (bytes + 255) & ~(size_t)255;
    return p;
  };
  bf16* xb   = (bf16*)alloc((size_t)N_TOK * Dm * 2);
  bf16* W1t  = (bf16*)alloc((size_t)Em * Fm * Dm * 2);
  bf16* W2t  = (bf16*)alloc((size_t)Em * Dm * Fm * 2);
  bf16* qw   = (bf16*)alloc((size_t)Dm * Dm * 2);
  bf16* kvw  = (bf16*)alloc((size_t)2 * Dm * Dm * 2);
  bf16* ow   = (bf16*)alloc((size_t)Dm * Dm * 2);
  float* bkv = (float*)alloc((size_t)2 * Dm * 4);
  bf16* hid  = (bf16*)alloc((size_t)Em * N_TOK * Fm * 2);   // 128 MB [e][n][f]
  bf16* eo   = (bf16*)alloc((size_t)N_TOK * Em * Dm * 2);   // [n][e][d]
  bf16* kv   = (bf16*)hid;                                  // alias: [n*E+e][2D]
  float* qb  = (float*)(hid + (size_t)N_TOK * Em * 2 * Dm);
  bf16* ctxb = (bf16*)(qb + (size_t)N_TOK * Dm);

  // ---- converts / transposes ----
  cvt_f32_bf16<<<(N_TOK * Dm / 4 + 255) / 256, 256, 0, stream>>>(x, xb, N_TOK * Dm / 4);
  transpose_cvt<<<dim3(Fm / 32, Dm / 32, Em), 256, 0, stream>>>(
      W1, W1t, Dm, Fm, (long)Dm * Fm, (long)Fm * Dm);
  transpose_cvt<<<dim3(Dm / 32, Fm / 32, Em), 256, 0, stream>>>(
      W2, W2t, Fm, Dm, (long)Fm * Dm, (long)Dm * Fm);
  int nw4 = Dm * Dm / 4;
  cvt_f32_bf16<<<(nw4 + 255) / 256, 256, 0, stream>>>(Wq, qw, nw4);
  cvt_f32_bf16<<<(nw4 + 255) / 256, 256, 0, stream>>>(Wk, kvw, nw4);
  cvt_f32_bf16<<<(nw4 + 255) / 256, 256, 0, stream>>>(Wv, kvw + (size_t)Dm * Dm, nw4);
  cvt_f32_bf16<<<(nw4 + 255) / 256, 256, 0, stream>>>(Wo, ow, nw4);
  hipMemcpyAsync(bkv, bk, Dm * sizeof(float), hipMemcpyDeviceToDevice, stream);
  hipMemcpyAsync(bkv + Dm, bv, Dm * sizeof(float), hipMemcpyDeviceToDevice, stream);

  // ---- FFN stage 1: hid[e] = relu(x @ W1[e] + b1[e])  M=4096 N=2048 K=512
  gemm_bs<true, true><<<dim3(32, 32, Em), 256, 0, stream>>>(
      xb, W1t, hid, b1, Dm, Dm, Dm, Fm,
      0L, (long)Fm * Dm, (long)N_TOK * Fm, (long)Fm);
  // ---- FFN stage 2: eo[n][e][:] = hid[e] @ W2[e] + b2[e]  M=4096 N=512 K=2048
  gemm_bs<false, true><<<dim3(32, 8, Em), 256, 0, stream>>>(
      hid, W2t, eo, b2, Fm, Fm, Fm, Em * Dm,
      (long)N_TOK * Fm, (long)Dm * Fm, (long)Dm, (long)Dm);
  // ---- K|V for all expert rows: M=32768 N=1024 K=512
  gemm_bs<false, true><<<dim3(256, 16, 1), 256, 0, stream>>>(
      eo, kvw, kv, bkv, Dm, Dm, Dm, 2 * Dm,
      0L, 0L, 0L, 0L);
  // ---- Q only for expert row e_id (small: 128^2 kernel)
  gemm_bt<false, false><<<dim3(N_TOK / 128, Dm / 128, 1), 256, 0, stream>>>(
      eo, qw, qb, bq, N_TOK, Dm, Dm, Em * Dm, Dm, Dm,
      0L, 0L, 0L, 0L, eid, Dm);
  // ---- attention over experts ----
  attn_kernel<<<N_TOK / 4, 256, 0, stream>>>(qb, kv, ctxb, eid);
  // ---- out projection -> d_out (fp32) ----
  gemm_bt<false, false><<<dim3(N_TOK / 128, Dm / 128, 1), 256, 0, stream>>>(
      ctxb, ow, (float*)d_out, bo, N_TOK, Dm, Dm, Dm, Dm, Dm,
      0L, 0L, 0L, 0L, nullptr, 0);
}

// Round 16
// 327.753 us; speedup vs baseline: 1.5273x; 1.5273x over previous
//
#include <hip/hip_runtime.h>
#include <hip/hip_bf16.h>

typedef __hip_bfloat16 bf16;
typedef __attribute__((ext_vector_type(4))) float f32x4;
typedef __attribute__((ext_vector_type(8))) short s16x8;

#define N_TOK 4096   // B*S
#define Dm    512
#define Fm    2048
#define Em    8

__device__ __forceinline__ float bf2f(bf16 v) { return __bfloat162float(v); }
__device__ __forceinline__ bf16  f2bf(float f) { return __float2bfloat16(f); }

// async global->LDS, 16B per lane; LDS dest is wave-uniform base + lane*16
#define GL16(g, l)                                                              \
  __builtin_amdgcn_global_load_lds(                                             \
      (const __attribute__((address_space(1))) void*)(g),                       \
      (__attribute__((address_space(3))) void*)(l), 16, 0, 0)

#define BAR()                                   \
  do {                                          \
    __builtin_amdgcn_s_barrier();               \
    asm volatile("" ::: "memory");              \
  } while (0)

// ---------------- fp32 -> bf16 flat convert ----------------------------------
__global__ void cvt_f32_bf16(const float* __restrict__ in, bf16* __restrict__ out, int n4) {
  int i = blockIdx.x * 256 + threadIdx.x;
  if (i >= n4) return;
  float4 v = reinterpret_cast<const float4*>(in)[i];
  bf16 tmp[4] = {f2bf(v.x), f2bf(v.y), f2bf(v.z), f2bf(v.w)};
  __builtin_memcpy(out + (size_t)i * 4, tmp, 8);
}

// ------- fused convert of the 4 DxD attention weights + bkv assembly ---------
// blocks 0..1023: matrix (b>>8) in {Wq, Wk, Wv, Wo}; block 1024: bkv floats.
__global__ void cvt_weights(const float* __restrict__ Wq, const float* __restrict__ Wk,
                            const float* __restrict__ Wv, const float* __restrict__ Wo,
                            const float* __restrict__ bk, const float* __restrict__ bv,
                            bf16* __restrict__ qw, bf16* __restrict__ kvw,
                            bf16* __restrict__ ow, float* __restrict__ bkv) {
  int b = blockIdx.x;
  if (b < 1024) {
    int which = b >> 8;
    int i = (b & 255) * 256 + threadIdx.x;  // 0..65535 float4's
    const float* src = which == 0 ? Wq : which == 1 ? Wk : which == 2 ? Wv : Wo;
    bf16* dst = which == 0 ? qw : which == 1 ? kvw
              : which == 2 ? (kvw + (size_t)Dm * Dm) : ow;
    float4 v = reinterpret_cast<const float4*>(src)[i];
    bf16 tmp[4] = {f2bf(v.x), f2bf(v.y), f2bf(v.z), f2bf(v.w)};
    __builtin_memcpy(dst + (size_t)i * 4, tmp, 8);
  } else {
    for (int j = threadIdx.x; j < Dm; j += 256) {
      bkv[j] = bk[j];
      bkv[Dm + j] = bv[j];
    }
  }
}

// ---------------- fp32 [R][C] -> bf16 [C][R] tiled transpose-convert ---------
__global__ void transpose_cvt(const float* __restrict__ in, bf16* __restrict__ out,
                              int R, int C, long inb, long outb) {
  in  += (long)blockIdx.z * inb;
  out += (long)blockIdx.z * outb;
  __shared__ float t[32][33];
  int tx = threadIdx.x & 31, ty = threadIdx.x >> 5;
  int c0 = blockIdx.x * 32, r0 = blockIdx.y * 32;
#pragma unroll
  for (int i = 0; i < 32; i += 8)
    t[ty + i][tx] = in[(long)(r0 + ty + i) * C + c0 + tx];
  __syncthreads();
#pragma unroll
  for (int i = 0; i < 32; i += 8)
    out[(long)(c0 + ty + i) * R + r0 + tx] = f2bf(t[tx][ty + i]);
}

// ==== 128x128 BK=32 bf16 GEMM, double-buffered, single barrier/iter (r16) ====
// C = A @ Bt^T (+bias[, relu]).  A:[M][K] lda, Bt:[N][K] ldb, C row-major ldc.
// The champion r1/r10 structure with its one measured defect fixed: r1 drains
// vmcnt immediately after issuing the stage (2nd __syncthreads), exposing full
// HBM/L2 latency every K-iter. Here (catalog T3-minimum "2-phase"):
//   top of iter t: vmcnt(0)         <- drains stage(t), issued ONE FULL
//                                      compute phase ago (~250-300cy covered)
//                  BAR()            <- staged data visible; also: all waves
//                                      finished reading buf(t-1) (their
//                                      ds_reads complete before their MFMAs,
//                                      which precede this barrier)
//   stage(t+1) -> buf((t+1)&1) == buf((t-1)&1)   safe post-barrier
//   ds_read frags (swizzled) + 32 MFMA (setprio)
// ONE barrier per K-iter (r1 had 2). LDS 2x16KB=32KB; regs ~64V+64A -> target
// 4 blocks/CU (__launch_bounds__(256,4); cross-block overlap per m114).
// Swizzle both sides (#21): stage source chunk (lane&3)^((row>>1)&3) with
// linear LDS dest; ds_read phys slot q^((r>>1)&3) -> 2-way max (free, m136;
// PMC-verified 0 conflicts r13/r14 with this exact XOR at BK=32).
// Swapped MFMA operands (verified r8-r10): acc[m][n][r] ->
// C[bm+wm*64+m*16+la][bn+wn*64+n*16+q*4+r] -> packed 8B/16B stores.
template <bool RELU, bool OUT_BF16>
__global__ __launch_bounds__(256, 4) void gemm128d(
    const bf16* __restrict__ A, const bf16* __restrict__ Bt, void* __restrict__ Cout,
    const float* __restrict__ bias, int K, int lda, int ldb, int ldc,
    long abs_, long bbs, long cbs, long biasbs,
    const int* __restrict__ eid, int eid_scale) {
  __shared__ bf16 As[2][128 * 32];
  __shared__ bf16 Bs[2][128 * 32];

  int e = blockIdx.z;
  A    += (long)e * abs_;
  Bt   += (long)e * bbs;
  bias += (long)e * biasbs;
  long coff = (long)e * cbs;
  if (eid) A += (long)(*eid) * eid_scale;

  int bm = blockIdx.x * 128, bn = blockIdx.y * 128;
  int tid = threadIdx.x, wv = tid >> 6, lane = tid & 63;
  int wm = wv >> 1, wn = wv & 1;
  int la = lane & 15, q = lane >> 4;
  int srow = lane >> 2;

  const bf16* Ab = A + (long)bm * lda;
  const bf16* Bb = Bt + (long)bn * ldb;
  int nt = K >> 5;  // BK = 32

  auto stage = [&](int t) {
    if (t >= nt) return;
    int k0 = t << 5;
    bf16* abuf = &As[t & 1][0];
    bf16* bbuf = &Bs[t & 1][0];
#pragma unroll
    for (int i = 0; i < 2; ++i) {
      int r = wv * 32 + i * 16 + srow;
      int c = (lane & 3) ^ ((r >> 1) & 3);  // inverse-swizzled source chunk
      GL16(Ab + (long)r * lda + k0 + c * 8, abuf + (wv * 32 + i * 16) * 32);
      GL16(Bb + (long)r * ldb + k0 + c * 8, bbuf + (wv * 32 + i * 16) * 32);
    }
  };

  f32x4 acc[4][4] = {};

  stage(0);  // prologue

  for (int t = 0; t < nt; ++t) {
    asm volatile("s_waitcnt vmcnt(0)" ::: "memory");  // stage(t) retired
    BAR();  // visible to all; all waves done reading buf(t-1)
    stage(t + 1);  // issue next tile; drain deferred one full compute phase
    const bf16* Abuf = &As[t & 1][0];
    const bf16* Bbuf = &Bs[t & 1][0];
    s16x8 af[4], bfr[4];
#pragma unroll
    for (int m = 0; m < 4; ++m) {
      int r = wm * 64 + m * 16 + la;
      af[m] = *reinterpret_cast<const s16x8*>(Abuf + r * 32 + (q ^ ((r >> 1) & 3)) * 8);
    }
#pragma unroll
    for (int n = 0; n < 4; ++n) {
      int r = wn * 64 + n * 16 + la;
      bfr[n] = *reinterpret_cast<const s16x8*>(Bbuf + r * 32 + (q ^ ((r >> 1) & 3)) * 8);
    }
    __builtin_amdgcn_s_setprio(1);
#pragma unroll
    for (int m = 0; m < 4; ++m)
#pragma unroll
      for (int n = 0; n < 4; ++n)
        acc[m][n] = __builtin_amdgcn_mfma_f32_16x16x32_bf16(bfr[n], af[m], acc[m][n], 0, 0, 0);
    __builtin_amdgcn_s_setprio(0);
  }

  // epilogue: acc[m][n][r] -> C[bm+wm*64+m*16+la][bn+wn*64+n*16+q*4+r]
#pragma unroll
  for (int m = 0; m < 4; ++m) {
    int gm = bm + wm * 64 + m * 16 + la;
#pragma unroll
    for (int n = 0; n < 4; ++n) {
      int gn = bn + wn * 64 + n * 16 + q * 4;
      float4 b4 = *reinterpret_cast<const float4*>(bias + gn);
      float v0 = acc[m][n][0] + b4.x, v1 = acc[m][n][1] + b4.y;
      float v2 = acc[m][n][2] + b4.z, v3 = acc[m][n][3] + b4.w;
      if (RELU) {
        v0 = fmaxf(v0, 0.f); v1 = fmaxf(v1, 0.f);
        v2 = fmaxf(v2, 0.f); v3 = fmaxf(v3, 0.f);
      }
      long idx = coff + (long)gm * ldc + gn;
      if (OUT_BF16) {
        bf16 tmp[4] = {f2bf(v0), f2bf(v1), f2bf(v2), f2bf(v3)};
        __builtin_memcpy((bf16*)Cout + idx, tmp, 8);
      } else {
        float tmp[4] = {v0, v1, v2, v3};
        __builtin_memcpy((float*)Cout + idx, tmp, 16);
      }
    }
  }
}

// ---------------- attention over the expert axis (E=8, H=8, HD=64) ----------
__global__ __launch_bounds__(256) void attn_kernel(const float* __restrict__ q,
                                                   const bf16* __restrict__ kv,
                                                   bf16* __restrict__ ctx,
                                                   const int* __restrict__ eid) {
  int wave = threadIdx.x >> 6, lane = threadIdx.x & 63;
  int n = blockIdx.x * 4 + wave;
  int h = lane >> 3, f = lane & 7;
  int e3 = *eid;
  const bf16* kvn = kv + (long)n * Em * (2 * Dm);
  const float* qh = q + (long)n * Dm + h * 64;
  const bf16* kf = kvn + f * (2 * Dm) + h * 64;
  float s = 0.f;
#pragma unroll
  for (int j = 0; j < 64; j++) s += qh[j] * bf2f(kf[j]);
  s *= 0.125f;
  s += (f <= e3) ? 1.0f : 0.0f;  // torch-faithful ADDITIVE float tril mask
  float mx = s;
#pragma unroll
  for (int d = 1; d < 8; d <<= 1) mx = fmaxf(mx, __shfl_xor(mx, d));
  float ex = expf(s - mx);
  float sm = ex;
#pragma unroll
  for (int d = 1; d < 8; d <<= 1) sm += __shfl_xor(sm, d);
  float at = ex / sm;
  int g = f;
  float acc[8] = {0, 0, 0, 0, 0, 0, 0, 0};
#pragma unroll
  for (int f2 = 0; f2 < 8; f2++) {
    float a = __shfl(at, (h << 3) | f2);
    const bf16* vf = kvn + f2 * (2 * Dm) + Dm + h * 64 + g * 8;
#pragma unroll
    for (int j = 0; j < 8; j++) acc[j] += a * bf2f(vf[j]);
  }
  bf16 tmp[8];
#pragma unroll
  for (int j = 0; j < 8; j++) tmp[j] = f2bf(acc[j]);
  __builtin_memcpy(ctx + (long)n * Dm + h * 64 + g * 8, tmp, 16);
}

extern "C" void kernel_launch(void* const* d_in, const int* in_sizes, int n_in,
                              void* d_out, int out_size, void* d_ws, size_t ws_size,
                              hipStream_t stream) {
  const float* x  = (const float*)d_in[0];
  const float* W1 = (const float*)d_in[1];
  const float* b1 = (const float*)d_in[2];
  const float* W2 = (const float*)d_in[3];
  const float* b2 = (const float*)d_in[4];
  const float* Wq = (const float*)d_in[5];
  const float* bq = (const float*)d_in[6];
  const float* Wk = (const float*)d_in[7];
  const float* bk = (const float*)d_in[8];
  const float* Wv = (const float*)d_in[9];
  const float* bv = (const float*)d_in[10];
  const float* Wo = (const float*)d_in[11];
  const float* bo = (const float*)d_in[12];
  const int* eid  = (const int*)d_in[13];

  char* w = (char*)d_ws;
  auto alloc = [&](size_t bytes) {
    char* p = w;
    w += (bytes + 255) & ~(size_t)255;
    return p;
  };
  bf16* xb   = (bf16*)alloc((size_t)N_TOK * Dm * 2);
  bf16* W1t  = (bf16*)alloc((size_t)Em * Fm * Dm * 2);
  bf16* W2t  = (bf16*)alloc((size_t)Em * Dm * Fm * 2);
  bf16* qw   = (bf16*)alloc((size_t)Dm * Dm * 2);
  bf16* kvw  = (bf16*)alloc((size_t)2 * Dm * Dm * 2);
  bf16* ow   = (bf16*)alloc((size_t)Dm * Dm * 2);
  float* bkv = (float*)alloc((size_t)2 * Dm * 4);
  bf16* hid  = (bf16*)alloc((size_t)Em * N_TOK * Fm * 2);   // 128 MB [e][n][f]
  bf16* eo   = (bf16*)alloc((size_t)N_TOK * Em * Dm * 2);   // [n][e][d]
  bf16* kv   = (bf16*)hid;                                  // alias: [n*E+e][2D]
  float* qb  = (float*)(hid + (size_t)N_TOK * Em * 2 * Dm);
  bf16* ctxb = (bf16*)(qb + (size_t)N_TOK * Dm);

  // ---- converts / transposes (trimmed: 4 launches total) ----
  cvt_f32_bf16<<<(N_TOK * Dm / 4 + 255) / 256, 256, 0, stream>>>(x, xb, N_TOK * Dm / 4);
  transpose_cvt<<<dim3(Fm / 32, Dm / 32, Em), 256, 0, stream>>>(
      W1, W1t, Dm, Fm, (long)Dm * Fm, (long)Fm * Dm);
  transpose_cvt<<<dim3(Dm / 32, Fm / 32, Em), 256, 0, stream>>>(
      W2, W2t, Fm, Dm, (long)Fm * Dm, (long)Dm * Fm);
  cvt_weights<<<1025, 256, 0, stream>>>(Wq, Wk, Wv, Wo, bk, bv, qw, kvw, ow, bkv);

  // ---- FFN stage 1: hid[e] = relu(x @ W1[e] + b1[e])  M=4096 N=2048 K=512
  gemm128d<true, true><<<dim3(32, 16, Em), 256, 0, stream>>>(
      xb, W1t, hid, b1, Dm, Dm, Dm, Fm,
      0L, (long)Fm * Dm, (long)N_TOK * Fm, (long)Fm, nullptr, 0);
  // ---- FFN stage 2: eo[n][e][:] = hid[e] @ W2[e] + b2[e]  M=4096 N=512 K=2048
  gemm128d<false, true><<<dim3(32, 4, Em), 256, 0, stream>>>(
      hid, W2t, eo, b2, Fm, Fm, Fm, Em * Dm,
      (long)N_TOK * Fm, (long)Dm * Fm, (long)Dm, (long)Dm, nullptr, 0);
  // ---- K|V for all expert rows: M=32768 N=1024 K=512
  gemm128d<false, true><<<dim3(256, 8, 1), 256, 0, stream>>>(
      eo, kvw, kv, bkv, Dm, Dm, Dm, 2 * Dm,
      0L, 0L, 0L, 0L, nullptr, 0);
  // ---- Q only for expert row e_id: M=4096 N=512 K=512
  gemm128d<false, false><<<dim3(32, 4, 1), 256, 0, stream>>>(
      eo, qw, qb, bq, Dm, Em * Dm, Dm, Dm,
      0L, 0L, 0L, 0L, eid, Dm);
  // ---- attention over experts ----
  attn_kernel<<<N_TOK / 4, 256, 0, stream>>>(qb, kv, ctxb, eid);
  // ---- out projection -> d_out (fp32): M=4096 N=512 K=512
  gemm128d<false, false><<<dim3(32, 4, 1), 256, 0, stream>>>(
      ctxb, ow, (float*)d_out, bo, Dm, Dm, Dm, Dm,
      0L, 0L, 0L, 0L, nullptr, 0);
}

// Round 17
// 295.958 us; speedup vs baseline: 1.6914x; 1.1074x over previous
//
#include <hip/hip_runtime.h>
#include <hip/hip_bf16.h>

typedef __hip_bfloat16 bf16;
typedef __attribute__((ext_vector_type(4))) float f32x4;
typedef __attribute__((ext_vector_type(8))) short s16x8;

#define N_TOK 4096   // B*S
#define Dm    512
#define Fm    2048
#define Em    8

__device__ __forceinline__ float bf2f(bf16 v) { return __bfloat162float(v); }
__device__ __forceinline__ bf16  f2bf(float f) { return __float2bfloat16(f); }

// async global->LDS, 16B per lane; LDS dest is wave-uniform base + lane*16
#define GL16(g, l)                                                              \
  __builtin_amdgcn_global_load_lds(                                             \
      (const __attribute__((address_space(1))) void*)(g),                       \
      (__attribute__((address_space(3))) void*)(l), 16, 0, 0)

// ---- fused convert: x (2048 blks) + 4 DxD weights (1024 blks) + bkv (1) ----
__global__ void cvt_all(const float* __restrict__ x, const float* __restrict__ Wq,
                        const float* __restrict__ Wk, const float* __restrict__ Wv,
                        const float* __restrict__ Wo, const float* __restrict__ bk,
                        const float* __restrict__ bv, bf16* __restrict__ xb,
                        bf16* __restrict__ qw, bf16* __restrict__ kvw,
                        bf16* __restrict__ ow, float* __restrict__ bkv) {
  int b = blockIdx.x;
  if (b < 2048) {  // x: 4096*512/4 = 524288 float4
    int i = b * 256 + threadIdx.x;
    float4 v = reinterpret_cast<const float4*>(x)[i];
    bf16 tmp[4] = {f2bf(v.x), f2bf(v.y), f2bf(v.z), f2bf(v.w)};
    __builtin_memcpy(xb + (size_t)i * 4, tmp, 8);
  } else if (b < 3072) {
    int bb = b - 2048;
    int which = bb >> 8;
    int i = (bb & 255) * 256 + threadIdx.x;  // 65536 float4 per matrix
    const float* src = which == 0 ? Wq : which == 1 ? Wk : which == 2 ? Wv : Wo;
    bf16* dst = which == 0 ? qw : which == 1 ? kvw
              : which == 2 ? (kvw + (size_t)Dm * Dm) : ow;
    float4 v = reinterpret_cast<const float4*>(src)[i];
    bf16 tmp[4] = {f2bf(v.x), f2bf(v.y), f2bf(v.z), f2bf(v.w)};
    __builtin_memcpy(dst + (size_t)i * 4, tmp, 8);
  } else {
    for (int j = threadIdx.x; j < Dm; j += 256) {
      bkv[j] = bk[j];
      bkv[Dm + j] = bv[j];
    }
  }
}

// ------ fp32 [R][C] -> bf16 [C][R] transpose-convert, packed 8B stores -------
// 32x32 tile; load coalesced scalar rows; store 4 consecutive bf16 (8B) per
// thread along the output row (G13: packed bf16 stores, 8x fewer store instrs
// than the scalar version).
__global__ void transpose_cvt(const float* __restrict__ in, bf16* __restrict__ out,
                              int R, int C, long inb, long outb) {
  in  += (long)blockIdx.z * inb;
  out += (long)blockIdx.z * outb;
  __shared__ float t[32][33];
  int tid = threadIdx.x;
  int col = tid & 31, row8 = tid >> 5;
  int c0 = blockIdx.x * 32, r0 = blockIdx.y * 32;
#pragma unroll
  for (int i = 0; i < 4; ++i)
    t[row8 + i * 8][col] = in[(long)(r0 + row8 + i * 8) * C + c0 + col];
  __syncthreads();
  int cc = tid >> 3, rb = (tid & 7) * 4;  // out[c0+cc][r0+rb .. +4]
  bf16 tmp[4];
#pragma unroll
  for (int k = 0; k < 4; ++k) tmp[k] = f2bf(t[rb + k][cc]);
  __builtin_memcpy(out + (long)(c0 + cc) * R + r0 + rb, tmp, 8);
}

// ======== 128x128 BK=64 bf16 GEMM (r10 champion, verbatim) ===================
// C = A @ Bt^T (+bias[, relu]).  A:[M][K] lda, Bt:[N][K] ldb, C row-major ldc.
// grid = (M/128, N/128, batch), natural order (r9: XCD remap thrashed L2).
// 4 waves (2x2), BK=64, 32 KB LDS, 2 barriers/K-iter — the measured optimum:
// every deviation (8-phase r8, 3-buf counted r13, 1-barrier deferred r16,
// LDS-free r11, small-acc r15) measured equal or slower. Chunk-XOR swizzle
// both sides (#21; PMC-verified 0 conflicts r9/r10). Swapped MFMA operands:
// acc[m][n][r] -> C[bm+wm*64+m*16+la][bn+wn*64+n*16+q*4+r], packed stores.
template <bool RELU, bool OUT_BF16>
__global__ __launch_bounds__(256, 4) void gemm128(
    const bf16* __restrict__ A, const bf16* __restrict__ Bt, void* __restrict__ Cout,
    const float* __restrict__ bias, int K, int lda, int ldb, int ldc,
    long abs_, long bbs, long cbs, long biasbs,
    const int* __restrict__ eid, int eid_scale) {
  __shared__ bf16 As[128 * 64];
  __shared__ bf16 Bs[128 * 64];

  int e  = blockIdx.z;
  int bm = blockIdx.x * 128, bn = blockIdx.y * 128;

  A    += (long)e * abs_;
  Bt   += (long)e * bbs;
  bias += (long)e * biasbs;
  long coff = (long)e * cbs;
  if (eid) A += (long)(*eid) * eid_scale;

  int tid = threadIdx.x, wv = tid >> 6, lane = tid & 63;
  int wm = wv >> 1, wn = wv & 1;

  const bf16* Ab = A + (long)bm * lda;
  const bf16* Bb = Bt + (long)bn * ldb;

  f32x4 acc[4][4] = {};
  int la = lane & 15, q = lane >> 4;
  int srow_lo = lane >> 3;  // staging row within 8-row group

  for (int k0 = 0; k0 < K; k0 += 64) {
    __syncthreads();  // previous compute done before overwrite
#pragma unroll
    for (int j = 0; j < 4; ++j) {
      int r = (wv * 4 + j) * 8 + srow_lo;
      int c = (lane & 7) ^ (r & 7);  // inverse-swizzled source chunk
      GL16(Ab + (long)r * lda + k0 + c * 8, As + (wv * 4 + j) * 512);
      GL16(Bb + (long)r * ldb + k0 + c * 8, Bs + (wv * 4 + j) * 512);
    }
    __syncthreads();  // drain (vmcnt 0): staged data visible

#pragma unroll
    for (int kk = 0; kk < 2; ++kk) {  // sequential kk keeps VGPR peak low
      int ps = (kk * 4 + q) ^ (la & 7);  // swizzled ds_read slot
      s16x8 af[4], bfr[4];
#pragma unroll
      for (int m = 0; m < 4; ++m)
        af[m] = *reinterpret_cast<const s16x8*>(As + (wm * 64 + m * 16 + la) * 64 + ps * 8);
#pragma unroll
      for (int n = 0; n < 4; ++n)
        bfr[n] = *reinterpret_cast<const s16x8*>(Bs + (wn * 64 + n * 16 + la) * 64 + ps * 8);
#pragma unroll
      for (int m = 0; m < 4; ++m)
#pragma unroll
        for (int n = 0; n < 4; ++n)
          acc[m][n] = __builtin_amdgcn_mfma_f32_16x16x32_bf16(bfr[n], af[m], acc[m][n], 0, 0, 0);
    }
  }

  // epilogue: acc[m][n][r] -> C[bm+wm*64+m*16+la][bn+wn*64+n*16+q*4+r]
#pragma unroll
  for (int m = 0; m < 4; ++m) {
    int gm = bm + wm * 64 + m * 16 + la;
#pragma unroll
    for (int n = 0; n < 4; ++n) {
      int gn = bn + wn * 64 + n * 16 + q * 4;
      float4 b4 = *reinterpret_cast<const float4*>(bias + gn);
      float v0 = acc[m][n][0] + b4.x, v1 = acc[m][n][1] + b4.y;
      float v2 = acc[m][n][2] + b4.z, v3 = acc[m][n][3] + b4.w;
      if (RELU) {
        v0 = fmaxf(v0, 0.f); v1 = fmaxf(v1, 0.f);
        v2 = fmaxf(v2, 0.f); v3 = fmaxf(v3, 0.f);
      }
      long idx = coff + (long)gm * ldc + gn;
      if (OUT_BF16) {
        bf16 tmp[4] = {f2bf(v0), f2bf(v1), f2bf(v2), f2bf(v3)};
        __builtin_memcpy((bf16*)Cout + idx, tmp, 8);
      } else {
        float tmp[4] = {v0, v1, v2, v3};
        __builtin_memcpy((float*)Cout + idx, tmp, 16);
      }
    }
  }
}

// ---------------- attention over the expert axis (E=8, H=8, HD=64) ----------
__global__ __launch_bounds__(256) void attn_kernel(const float* __restrict__ q,
                                                   const bf16* __restrict__ kv,
                                                   bf16* __restrict__ ctx,
                                                   const int* __restrict__ eid) {
  int wave = threadIdx.x >> 6, lane = threadIdx.x & 63;
  int n = blockIdx.x * 4 + wave;
  int h = lane >> 3, f = lane & 7;
  int e3 = *eid;
  const bf16* kvn = kv + (long)n * Em * (2 * Dm);
  const float* qh = q + (long)n * Dm + h * 64;
  const bf16* kf = kvn + f * (2 * Dm) + h * 64;
  float s = 0.f;
#pragma unroll
  for (int j = 0; j < 64; j++) s += qh[j] * bf2f(kf[j]);
  s *= 0.125f;
  s += (f <= e3) ? 1.0f : 0.0f;  // torch-faithful ADDITIVE float tril mask
  float mx = s;
#pragma unroll
  for (int d = 1; d < 8; d <<= 1) mx = fmaxf(mx, __shfl_xor(mx, d));
  float ex = expf(s - mx);
  float sm = ex;
#pragma unroll
  for (int d = 1; d < 8; d <<= 1) sm += __shfl_xor(sm, d);
  float at = ex / sm;
  int g = f;
  float acc[8] = {0, 0, 0, 0, 0, 0, 0, 0};
#pragma unroll
  for (int f2 = 0; f2 < 8; f2++) {
    float a = __shfl(at, (h << 3) | f2);
    const bf16* vf = kvn + f2 * (2 * Dm) + Dm + h * 64 + g * 8;
#pragma unroll
    for (int j = 0; j < 8; j++) acc[j] += a * bf2f(vf[j]);
  }
  bf16 tmp[8];
#pragma unroll
  for (int j = 0; j < 8; j++) tmp[j] = f2bf(acc[j]);
  __builtin_memcpy(ctx + (long)n * Dm + h * 64 + g * 8, tmp, 16);
}

extern "C" void kernel_launch(void* const* d_in, const int* in_sizes, int n_in,
                              void* d_out, int out_size, void* d_ws, size_t ws_size,
                              hipStream_t stream) {
  const float* x  = (const float*)d_in[0];
  const float* W1 = (const float*)d_in[1];
  const float* b1 = (const float*)d_in[2];
  const float* W2 = (const float*)d_in[3];
  const float* b2 = (const float*)d_in[4];
  const float* Wq = (const float*)d_in[5];
  const float* bq = (const float*)d_in[6];
  const float* Wk = (const float*)d_in[7];
  const float* bk = (const float*)d_in[8];
  const float* Wv = (const float*)d_in[9];
  const float* bv = (const float*)d_in[10];
  const float* Wo = (const float*)d_in[11];
  const float* bo = (const float*)d_in[12];
  const int* eid  = (const int*)d_in[13];

  char* w = (char*)d_ws;
  auto alloc = [&](size_t bytes) {
    char* p = w;
    w += (bytes + 255) & ~(size_t)255;
    return p;
  };
  bf16* xb   = (bf16*)alloc((size_t)N_TOK * Dm * 2);
  bf16* W1t  = (bf16*)alloc((size_t)Em * Fm * Dm * 2);
  bf16* W2t  = (bf16*)alloc((size_t)Em * Dm * Fm * 2);
  bf16* qw   = (bf16*)alloc((size_t)Dm * Dm * 2);
  bf16* kvw  = (bf16*)alloc((size_t)2 * Dm * Dm * 2);
  bf16* ow   = (bf16*)alloc((size_t)Dm * Dm * 2);
  float* bkv = (float*)alloc((size_t)2 * Dm * 4);
  bf16* hid  = (bf16*)alloc((size_t)Em * N_TOK * Fm * 2);   // 128 MB [e][n][f]
  bf16* eo   = (bf16*)alloc((size_t)N_TOK * Em * Dm * 2);   // [n][e][d]
  bf16* kv   = (bf16*)hid;                                  // alias: [n*E+e][2D]
  float* qb  = (float*)(hid + (size_t)N_TOK * Em * 2 * Dm);
  bf16* ctxb = (bf16*)(qb + (size_t)N_TOK * Dm);

  // ---- converts / transposes (3 launches) ----
  cvt_all<<<3073, 256, 0, stream>>>(x, Wq, Wk, Wv, Wo, bk, bv, xb, qw, kvw, ow, bkv);
  transpose_cvt<<<dim3(Fm / 32, Dm / 32, Em), 256, 0, stream>>>(
      W1, W1t, Dm, Fm, (long)Dm * Fm, (long)Fm * Dm);
  transpose_cvt<<<dim3(Dm / 32, Fm / 32, Em), 256, 0, stream>>>(
      W2, W2t, Fm, Dm, (long)Fm * Dm, (long)Dm * Fm);

  // ---- FFN stage 1: hid[e] = relu(x @ W1[e] + b1[e])  M=4096 N=2048 K=512
  gemm128<true, true><<<dim3(32, 16, Em), 256, 0, stream>>>(
      xb, W1t, hid, b1, Dm, Dm, Dm, Fm,
      0L, (long)Fm * Dm, (long)N_TOK * Fm, (long)Fm, nullptr, 0);
  // ---- FFN stage 2: eo[n][e][:] = hid[e] @ W2[e] + b2[e]  M=4096 N=512 K=2048
  gemm128<false, true><<<dim3(32, 4, Em), 256, 0, stream>>>(
      hid, W2t, eo, b2, Fm, Fm, Fm, Em * Dm,
      (long)N_TOK * Fm, (long)Dm * Fm, (long)Dm, (long)Dm, nullptr, 0);
  // ---- K|V for all expert rows: M=32768 N=1024 K=512
  gemm128<false, true><<<dim3(256, 8, 1), 256, 0, stream>>>(
      eo, kvw, kv, bkv, Dm, Dm, Dm, 2 * Dm,
      0L, 0L, 0L, 0L, nullptr, 0);
  // ---- Q only for expert row e_id: M=4096 N=512 K=512
  gemm128<false, false><<<dim3(32, 4, 1), 256, 0, stream>>>(
      eo, qw, qb, bq, Dm, Em * Dm, Dm, Dm,
      0L, 0L, 0L, 0L, eid, Dm);
  // ---- attention over experts ----
  attn_kernel<<<N_TOK / 4, 256, 0, stream>>>(qb, kv, ctxb, eid);
  // ---- out projection -> d_out (fp32): M=4096 N=512 K=512
  gemm128<false, false><<<dim3(32, 4, 1), 256, 0, stream>>>(
      ctxb, ow, (float*)d_out, bo, Dm, Dm, Dm, Dm,
      0L, 0L, 0L, 0L, nullptr, 0);
}